// Round 1
// baseline (2229.346 us; speedup 1.0000x reference)
//
#include <hip/hip_runtime.h>
#include <math.h>

// LSTMModel: B=1024, T=512, D=32, H=64, 2 LSTM layers + fc1(relu) + fc2.
// Strategy (round 0, fp32-correct baseline):
//   block = 256 threads (4 waves) handles NB=2 batch elements for all T steps.
//   thread j = gate j (0..255, PyTorch order i,f,g,o) for both layers.
//   Weight rows W_hh_l0/W_ih_l1/W_hh_l1 live in per-thread VGPRs (192 floats).
//   W_ih_l0 (256x32) staged in LDS (x-part is only 32 MACs/gate).
//   h broadcast via v_readlane (VALU pipe) -- avoids LDS-issue-bound broadcast.
//   i/f/g/o -> (c,h) update by threads 0..127, exchanged via small LDS bufs.

namespace {

constexpr int Hh = 64;    // hidden
constexpr int Dd = 32;    // input dim
constexpr int Tt = 512;   // timesteps
constexpr int NG = 256;   // 4*H gates

__device__ __forceinline__ float rlane(float v, int l) {
    return __int_as_float(__builtin_amdgcn_readlane(__float_as_int(v), l));
}
__device__ __forceinline__ float sigm(float x) {
    return 1.0f / (1.0f + __expf(-x));
}
__device__ __forceinline__ float tanh_f(float x) {
    // 1 - 2/(e^{2x}+1); saturates gracefully at +/-1
    return 1.0f - 2.0f / (__expf(2.0f * x) + 1.0f);
}

__global__ __launch_bounds__(256, 2) void lstm_fused(
    const float* __restrict__ x,     // [B, T, D]
    const float* __restrict__ Wih0,  // [256, 32]
    const float* __restrict__ Whh0,  // [256, 64]
    const float* __restrict__ bih0,  // [256]
    const float* __restrict__ bhh0,  // [256]
    const float* __restrict__ Wih1,  // [256, 64]
    const float* __restrict__ Whh1,  // [256, 64]
    const float* __restrict__ bih1,  // [256]
    const float* __restrict__ bhh1,  // [256]
    const float* __restrict__ fc1w,  // [32, 64]
    const float* __restrict__ fc1b,  // [32]
    const float* __restrict__ fc2w,  // [1, 32]
    const float* __restrict__ fc2b,  // [1]
    float* __restrict__ out)         // [B, 1]
{
    __shared__ float s_wih0[NG * Dd];  // 32 KB
    __shared__ float s_g[2][NG];       // gate exchange, 2 batch
    __shared__ float s_h0[2][Hh];
    __shared__ float s_h1[2][Hh];
    __shared__ float s_fc[2][32];

    const int tid = threadIdx.x;
    const int j = tid;                 // gate index
    const int lane = tid & 63;
    const int b0 = blockIdx.x * 2;

    // stage Wih0 into LDS (coalesced float4)
    for (int i = tid; i < NG * Dd / 4; i += 256)
        ((float4*)s_wih0)[i] = ((const float4*)Wih0)[i];

    // per-thread weight rows -> VGPRs
    float whh0[Hh], wih1[Hh], whh1[Hh];
#pragma unroll
    for (int k = 0; k < Hh / 4; ++k) {
        float4 a = ((const float4*)(Whh0 + j * Hh))[k];
        whh0[4 * k + 0] = a.x; whh0[4 * k + 1] = a.y;
        whh0[4 * k + 2] = a.z; whh0[4 * k + 3] = a.w;
        float4 b = ((const float4*)(Wih1 + j * Hh))[k];
        wih1[4 * k + 0] = b.x; wih1[4 * k + 1] = b.y;
        wih1[4 * k + 2] = b.z; wih1[4 * k + 3] = b.w;
        float4 c = ((const float4*)(Whh1 + j * Hh))[k];
        whh1[4 * k + 0] = c.x; whh1[4 * k + 1] = c.y;
        whh1[4 * k + 2] = c.z; whh1[4 * k + 3] = c.w;
    }
    const float xb0 = bih0[j] + bhh0[j];
    const float xb1 = bih1[j] + bhh1[j];

    // update-phase mapping (threads 0..127): batch ub, unit uk
    const int ub = tid >> 6;
    const int uk = tid & 63;

    // x addressing: lanes 0..31 -> batch b0, d=lane; lanes 32..63 -> b0+1, d=lane-32
    const float* xlane =
        x + ((size_t)(b0 + (lane >> 5)) * Tt) * Dd + (lane & 31);

    float vh0a = 0.f, vh0b = 0.f, vh1a = 0.f, vh1b = 0.f;
    float c0 = 0.f, c1 = 0.f;  // only meaningful for tid<128

    __syncthreads();

    for (int t = 0; t < Tt; ++t) {
        const float vx = xlane[0];  // x[b][t][d] per lane
        // ---- layer 0 gates ----
        float a0 = xb0, a1 = xb0;
#pragma unroll
        for (int d = 0; d < Dd; d += 4) {
            float4 w4 = *(const float4*)&s_wih0[j * Dd + d];
            a0 = fmaf(w4.x, rlane(vx, d + 0), a0);
            a1 = fmaf(w4.x, rlane(vx, 32 + d + 0), a1);
            a0 = fmaf(w4.y, rlane(vx, d + 1), a0);
            a1 = fmaf(w4.y, rlane(vx, 32 + d + 1), a1);
            a0 = fmaf(w4.z, rlane(vx, d + 2), a0);
            a1 = fmaf(w4.z, rlane(vx, 32 + d + 2), a1);
            a0 = fmaf(w4.w, rlane(vx, d + 3), a0);
            a1 = fmaf(w4.w, rlane(vx, 32 + d + 3), a1);
        }
#pragma unroll
        for (int k = 0; k < Hh; ++k) {
            a0 = fmaf(whh0[k], rlane(vh0a, k), a0);
            a1 = fmaf(whh0[k], rlane(vh0b, k), a1);
        }
        s_g[0][j] = a0;
        s_g[1][j] = a1;
        __syncthreads();
        if (tid < 128) {
            const float gi = sigm(s_g[ub][uk]);
            const float gf = sigm(s_g[ub][64 + uk]);
            const float gg = tanh_f(s_g[ub][128 + uk]);
            const float go = sigm(s_g[ub][192 + uk]);
            c0 = gf * c0 + gi * gg;
            s_h0[ub][uk] = go * tanh_f(c0);
        }
        __syncthreads();
        vh0a = s_h0[0][lane];
        vh0b = s_h0[1][lane];
        // ---- layer 1 gates ----
        a0 = xb1; a1 = xb1;
#pragma unroll
        for (int k = 0; k < Hh; ++k) {
            a0 = fmaf(wih1[k], rlane(vh0a, k), a0);
            a1 = fmaf(wih1[k], rlane(vh0b, k), a1);
        }
#pragma unroll
        for (int k = 0; k < Hh; ++k) {
            a0 = fmaf(whh1[k], rlane(vh1a, k), a0);
            a1 = fmaf(whh1[k], rlane(vh1b, k), a1);
        }
        s_g[0][j] = a0;
        s_g[1][j] = a1;
        __syncthreads();
        if (tid < 128) {
            const float gi = sigm(s_g[ub][uk]);
            const float gf = sigm(s_g[ub][64 + uk]);
            const float gg = tanh_f(s_g[ub][128 + uk]);
            const float go = sigm(s_g[ub][192 + uk]);
            c1 = gf * c1 + gi * gg;
            s_h1[ub][uk] = go * tanh_f(c1);
        }
        __syncthreads();
        vh1a = s_h1[0][lane];
        vh1b = s_h1[1][lane];
        xlane += Dd;
    }

    // ---- FC epilogue: s_h1 holds h2(T-1) for both batch elems ----
    if (tid < 64) {
        const int fb = tid >> 5, fk = tid & 31;
        float acc = fc1b[fk];
#pragma unroll
        for (int d2 = 0; d2 < Hh; ++d2)
            acc = fmaf(fc1w[fk * Hh + d2], s_h1[fb][d2], acc);
        s_fc[fb][fk] = fmaxf(acc, 0.f);
    }
    __syncthreads();
    if (tid < 2) {
        float acc = fc2b[0];
#pragma unroll
        for (int d2 = 0; d2 < 32; ++d2)
            acc = fmaf(fc2w[d2], s_fc[tid][d2], acc);
        out[b0 + tid] = acc;
    }
}

}  // namespace

extern "C" void kernel_launch(void* const* d_in, const int* in_sizes, int n_in,
                              void* d_out, int out_size, void* d_ws, size_t ws_size,
                              hipStream_t stream) {
    const float* x    = (const float*)d_in[0];
    const float* Wih0 = (const float*)d_in[1];
    const float* Whh0 = (const float*)d_in[2];
    const float* bih0 = (const float*)d_in[3];
    const float* bhh0 = (const float*)d_in[4];
    const float* Wih1 = (const float*)d_in[5];
    const float* Whh1 = (const float*)d_in[6];
    const float* bih1 = (const float*)d_in[7];
    const float* bhh1 = (const float*)d_in[8];
    const float* fc1w = (const float*)d_in[9];
    const float* fc1b = (const float*)d_in[10];
    const float* fc2w = (const float*)d_in[11];
    const float* fc2b = (const float*)d_in[12];
    float* out = (float*)d_out;

    const int B = 1024;
    lstm_fused<<<dim3(B / 2), dim3(256), 0, stream>>>(
        x, Wih0, Whh0, bih0, bhh0, Wih1, Whh1, bih1, bhh1,
        fc1w, fc1b, fc2w, fc2b, out);
}

// Round 2
// 1222.736 us; speedup vs baseline: 1.8232x; 1.8232x over previous
//
#include <hip/hip_runtime.h>
#include <math.h>

// LSTMModel B=1024 T=512 D=32 H=64, 2 layers + fc1(relu) + fc2.
// Round 2: MFMA (bf16 split-2, 3 products) for all gate matmuls.
//   grid = 64 blocks (16 batches each), block = 1024 threads = 16 waves.
//   wave w owns gate rows 16w..16w+15; weights persist in VGPRs as split
//   bf16 A-fragments. h/x fragments exchanged via lane-linear LDS buffers
//   (conflict-free ds_read_b128). fp32 cell update, 1 thread = (unit,batch).
//   4 barriers/step. x prefetched one step ahead.

namespace {

constexpr int Hh = 64, Dd = 32, Tt = 512, NG = 256;

typedef __bf16 bf16x8 __attribute__((ext_vector_type(8)));
typedef float f32x4 __attribute__((ext_vector_type(4)));

__device__ __forceinline__ f32x4 mfma16(bf16x8 a, bf16x8 b, f32x4 c) {
    return __builtin_amdgcn_mfma_f32_16x16x32_bf16(a, b, c, 0, 0, 0);
}
__device__ __forceinline__ void split2(float v, __bf16& hi, __bf16& lo) {
    hi = (__bf16)v;
    lo = (__bf16)(v - (float)hi);
}
__device__ __forceinline__ float sigm(float x) { return 1.0f / (1.0f + __expf(-x)); }
__device__ __forceinline__ float tanh_(float x) { return 1.0f - 2.0f / (__expf(2.0f * x) + 1.0f); }

__device__ __forceinline__ void load_afrag(const float* p, bf16x8& ah, bf16x8& al) {
#pragma unroll
    for (int e = 0; e < 8; ++e) {
        float v = p[e];
        __bf16 h, l;
        split2(v, h, l);
        ah[e] = h;
        al[e] = l;
    }
}
__device__ __forceinline__ bf16x8 ldfrag(const __bf16* p) {
    return *(const bf16x8*)p;
}

__global__ __launch_bounds__(1024, 4) void lstm_mfma(
    const float* __restrict__ x,     // [B, T, D]
    const float* __restrict__ Wih0,  // [256, 32]
    const float* __restrict__ Whh0,  // [256, 64]
    const float* __restrict__ bih0, const float* __restrict__ bhh0,
    const float* __restrict__ Wih1,  // [256, 64]
    const float* __restrict__ Whh1,  // [256, 64]
    const float* __restrict__ bih1, const float* __restrict__ bhh1,
    const float* __restrict__ fc1w,  // [32, 64]
    const float* __restrict__ fc1b,  // [32]
    const float* __restrict__ fc2w,  // [1, 32]
    const float* __restrict__ fc2b,  // [1]
    float* __restrict__ out)         // [B]
{
    // B-operand fragment buffers, lane-linear: frag[lane][e] (ds_read_b128).
    __shared__ __align__(16) __bf16 s_bx[2][64][8];        // x tile, K=32
    __shared__ __align__(16) __bf16 s_bh0[2][2][64][8];    // h0, K=64 (2 kt)
    __shared__ __align__(16) __bf16 s_bh1[2][2][64][8];    // h1, K=64
    __shared__ float s_pre[NG][17];                        // preacts (+pad)
    __shared__ float s_hf[Hh][17];                         // h1 fp32 (last t)
    __shared__ float s_fc[32][17];

    const int tid = threadIdx.x;
    const int w = tid >> 6;    // wave 0..15
    const int l = tid & 63;    // lane
    const int gbase = w * 16;
    const int ar = l & 15;     // A-operand row within tile
    const int akb = l >> 4;    // A/B k-group (k = akb*8 + e)
    const int cq = l >> 4;     // C/D: row = cq*4 + r
    const int cj = l & 15;     // C/D: col = batch
    const int b0 = blockIdx.x * 16;

    // ---- persistent A fragments (split-2 bf16) ----
    bf16x8 a0h[3], a0l[3], a1h[4], a1l[4];
    {
        const int g = gbase + ar;
        load_afrag(Wih0 + g * 32 + akb * 8,      a0h[0], a0l[0]); // x part
        load_afrag(Whh0 + g * 64 + akb * 8,      a0h[1], a0l[1]); // h0 k0..31
        load_afrag(Whh0 + g * 64 + 32 + akb * 8, a0h[2], a0l[2]); // h0 k32..63
        load_afrag(Wih1 + g * 64 + akb * 8,      a1h[0], a1l[0]); // h0 k0..31
        load_afrag(Wih1 + g * 64 + 32 + akb * 8, a1h[1], a1l[1]); // h0 k32..63
        load_afrag(Whh1 + g * 64 + akb * 8,      a1h[2], a1l[2]); // h1 k0..31
        load_afrag(Whh1 + g * 64 + 32 + akb * 8, a1h[3], a1l[3]); // h1 k32..63
    }
    // biases folded into acc init (C/D row mapping)
    f32x4 bias0v, bias1v;
#pragma unroll
    for (int r = 0; r < 4; ++r) {
        const int gg = gbase + cq * 4 + r;
        bias0v[r] = bih0[gg] + bhh0[gg];
        bias1v[r] = bih1[gg] + bhh1[gg];
    }

    // ---- update-phase mapping: thread = (unit uu, batch uj) ----
    const int uu = tid >> 4;          // 0..63
    const int uj = tid & 15;
    const int fkt = uu >> 5;          // which K-tile of h frag
    const int fkk = uu & 31;
    const int flane = ((fkk >> 3) << 4) | uj;
    const int fe = fkk & 7;

    float c0 = 0.f, c1 = 0.f;

    // ---- x prefetch (threads 0..511: 1 element = (batch bx, dim kx)) ----
    const int kx = tid & 31;
    const int bx = (tid >> 5) & 15;
    const float* xptr = x + ((size_t)(b0 + bx) * Tt) * Dd + kx;
    float rx = (tid < 512) ? xptr[0] : 0.f;

    // zero-init h fragment buffers (h(-1) = 0)
    ((int*)s_bh0)[tid] = 0;   // 1024 ints = 4KB
    ((int*)s_bh1)[tid] = 0;

    for (int t = 0; t < Tt; ++t) {
        // P1: publish x frag for step t, prefetch t+1
        if (tid < 512) {
            __bf16 h, lo;
            split2(rx, h, lo);
            const int fl = ((kx >> 3) << 4) | bx;
            s_bx[0][fl][kx & 7] = h;
            s_bx[1][fl][kx & 7] = lo;
            const int tn = (t + 1 < Tt) ? t + 1 : Tt - 1;
            rx = xptr[(size_t)tn * Dd];
        }
        __syncthreads();  // A

        // P2: layer-0 gates = [Wih0|Whh0] @ [x; h0]
        {
            f32x4 accA = bias0v;
            f32x4 accB = {0.f, 0.f, 0.f, 0.f};
            f32x4 accC = {0.f, 0.f, 0.f, 0.f};
            bf16x8 bh = ldfrag(&s_bx[0][l][0]);
            bf16x8 bl = ldfrag(&s_bx[1][l][0]);
            accA = mfma16(a0h[0], bh, accA);
            accB = mfma16(a0h[0], bl, accB);
            accC = mfma16(a0l[0], bh, accC);
            bh = ldfrag(&s_bh0[0][0][l][0]);
            bl = ldfrag(&s_bh0[1][0][l][0]);
            accA = mfma16(a0h[1], bh, accA);
            accB = mfma16(a0h[1], bl, accB);
            accC = mfma16(a0l[1], bh, accC);
            bh = ldfrag(&s_bh0[0][1][l][0]);
            bl = ldfrag(&s_bh0[1][1][l][0]);
            accA = mfma16(a0h[2], bh, accA);
            accB = mfma16(a0h[2], bl, accB);
            accC = mfma16(a0l[2], bh, accC);
            const f32x4 pre = accA + accB + accC;
#pragma unroll
            for (int r = 0; r < 4; ++r)
                s_pre[gbase + cq * 4 + r][cj] = pre[r];
        }
        __syncthreads();  // B

        // P3: layer-0 cell update -> h0 frags
        {
            const float pi = s_pre[uu][uj];
            const float pf = s_pre[64 + uu][uj];
            const float pg = s_pre[128 + uu][uj];
            const float po = s_pre[192 + uu][uj];
            const float gi = sigm(pi), gf = sigm(pf);
            const float gg = tanh_(pg), go = sigm(po);
            c0 = gf * c0 + gi * gg;
            const float h0 = go * tanh_(c0);
            __bf16 hh, hl;
            split2(h0, hh, hl);
            s_bh0[0][fkt][flane][fe] = hh;
            s_bh0[1][fkt][flane][fe] = hl;
        }
        __syncthreads();  // C

        // P4: layer-1 gates = [Wih1|Whh1] @ [h0(t); h1(t-1)]
        {
            f32x4 accA = bias1v;
            f32x4 accB = {0.f, 0.f, 0.f, 0.f};
            f32x4 accC = {0.f, 0.f, 0.f, 0.f};
            bf16x8 bh = ldfrag(&s_bh0[0][0][l][0]);
            bf16x8 bl = ldfrag(&s_bh0[1][0][l][0]);
            accA = mfma16(a1h[0], bh, accA);
            accB = mfma16(a1h[0], bl, accB);
            accC = mfma16(a1l[0], bh, accC);
            bh = ldfrag(&s_bh0[0][1][l][0]);
            bl = ldfrag(&s_bh0[1][1][l][0]);
            accA = mfma16(a1h[1], bh, accA);
            accB = mfma16(a1h[1], bl, accB);
            accC = mfma16(a1l[1], bh, accC);
            bh = ldfrag(&s_bh1[0][0][l][0]);
            bl = ldfrag(&s_bh1[1][0][l][0]);
            accA = mfma16(a1h[2], bh, accA);
            accB = mfma16(a1h[2], bl, accB);
            accC = mfma16(a1l[2], bh, accC);
            bh = ldfrag(&s_bh1[0][1][l][0]);
            bl = ldfrag(&s_bh1[1][1][l][0]);
            accA = mfma16(a1h[3], bh, accA);
            accB = mfma16(a1h[3], bl, accB);
            accC = mfma16(a1l[3], bh, accC);
            const f32x4 pre = accA + accB + accC;
#pragma unroll
            for (int r = 0; r < 4; ++r)
                s_pre[gbase + cq * 4 + r][cj] = pre[r];
        }
        __syncthreads();  // D

        // P5: layer-1 cell update -> h1 frags (no trailing barrier needed:
        // next readers of s_bh1 are behind next iter's A/B/C barriers)
        {
            const float pi = s_pre[uu][uj];
            const float pf = s_pre[64 + uu][uj];
            const float pg = s_pre[128 + uu][uj];
            const float po = s_pre[192 + uu][uj];
            const float gi = sigm(pi), gf = sigm(pf);
            const float gg = tanh_(pg), go = sigm(po);
            c1 = gf * c1 + gi * gg;
            const float h1v = go * tanh_(c1);
            __bf16 hh, hl;
            split2(h1v, hh, hl);
            s_bh1[0][fkt][flane][fe] = hh;
            s_bh1[1][fkt][flane][fe] = hl;
            if (t == Tt - 1) s_hf[uu][uj] = h1v;
        }
    }

    // ---- FC epilogue (fp32 VALU) ----
    __syncthreads();
    // stage fc1w into s_pre storage, padded [32][65]
    float* s_fcw = &s_pre[0][0];
    for (int i = tid; i < 32 * 64; i += 1024) {
        const int m = i >> 6, u = i & 63;
        s_fcw[m * 65 + u] = fc1w[i];
    }
    __syncthreads();
    if (tid < 512) {
        const int m = tid >> 4, jj = tid & 15;
        float acc = fc1b[m];
#pragma unroll
        for (int u = 0; u < Hh; ++u)
            acc = fmaf(s_fcw[m * 65 + u], s_hf[u][jj], acc);
        s_fc[m][jj] = fmaxf(acc, 0.f);
    }
    __syncthreads();
    if (tid < 16) {
        float acc = fc2b[0];
#pragma unroll
        for (int m = 0; m < 32; ++m)
            acc = fmaf(fc2w[m], s_fc[m][tid], acc);
        out[b0 + tid] = acc;
    }
}

}  // namespace

extern "C" void kernel_launch(void* const* d_in, const int* in_sizes, int n_in,
                              void* d_out, int out_size, void* d_ws, size_t ws_size,
                              hipStream_t stream) {
    const float* x    = (const float*)d_in[0];
    const float* Wih0 = (const float*)d_in[1];
    const float* Whh0 = (const float*)d_in[2];
    const float* bih0 = (const float*)d_in[3];
    const float* bhh0 = (const float*)d_in[4];
    const float* Wih1 = (const float*)d_in[5];
    const float* Whh1 = (const float*)d_in[6];
    const float* bih1 = (const float*)d_in[7];
    const float* bhh1 = (const float*)d_in[8];
    const float* fc1w = (const float*)d_in[9];
    const float* fc1b = (const float*)d_in[10];
    const float* fc2w = (const float*)d_in[11];
    const float* fc2b = (const float*)d_in[12];
    float* out = (float*)d_out;

    lstm_mfma<<<dim3(64), dim3(1024), 0, stream>>>(
        x, Wih0, Whh0, bih0, bhh0, Wih1, Whh1, bih1, bhh1,
        fc1w, fc1b, fc2w, fc2b, out);
}

// Round 3
// 780.817 us; speedup vs baseline: 2.8551x; 1.5660x over previous
//
#include <hip/hip_runtime.h>
#include <math.h>

// LSTMModel B=1024 T=512 D=32 H=64, 2 layers + fc1(relu) + fc2.
// Round 3: fp16 single-product MFMA, ONE barrier per step.
//   grid = 64 blocks x 1024 thr (16 waves); block owns 16 batches, all T.
//   A-row permutation gmap(m) = (m&3)*64 + 4w + (m>>2) makes lane (cq,cj)'s
//   acc[0..3] = (i,f,g,o) of unit u=4w+cq, batch cj -> in-register cell
//   update, no gate exchange. Layer1 lags layer0 by 1 step (skew pipeline)
//   so both layers share one MFMA+update phase -> 1 __syncthreads()/step.
//   h0/h1/x frag buffers parity double-buffered. x prefetch depth 2.

namespace {

constexpr int Hh = 64, Dd = 32, Tt = 512;

typedef _Float16 f16x8 __attribute__((ext_vector_type(8)));
typedef float f32x4 __attribute__((ext_vector_type(4)));

__device__ __forceinline__ f32x4 mfma(f16x8 a, f16x8 b, f32x4 c) {
    return __builtin_amdgcn_mfma_f32_16x16x32_f16(a, b, c, 0, 0, 0);
}
__device__ __forceinline__ float sigm(float v) { return 1.0f / (1.0f + __expf(-v)); }
__device__ __forceinline__ float tanh_(float v) { return 1.0f - 2.0f / (__expf(2.0f * v) + 1.0f); }

__device__ __forceinline__ f16x8 cvt8(const float* p) {
    f16x8 r;
#pragma unroll
    for (int e = 0; e < 8; ++e) r[e] = (_Float16)p[e];
    return r;
}

__global__ __launch_bounds__(1024, 4) void lstm_f16(
    const float* __restrict__ x,     // [B, T, D]
    const float* __restrict__ Wih0,  // [256, 32]
    const float* __restrict__ Whh0,  // [256, 64]
    const float* __restrict__ bih0, const float* __restrict__ bhh0,
    const float* __restrict__ Wih1,  // [256, 64]
    const float* __restrict__ Whh1,  // [256, 64]
    const float* __restrict__ bih1, const float* __restrict__ bhh1,
    const float* __restrict__ fc1w,  // [32, 64]
    const float* __restrict__ fc1b,  // [32]
    const float* __restrict__ fc2w,  // [1, 32]
    const float* __restrict__ fc2b,  // [1]
    float* __restrict__ out)         // [B]
{
    // B-fragment buffers, lane-linear (frag[lane][e]), parity double-buffered.
    __shared__ __align__(16) _Float16 s_x[2][64][8];        // x(t),  2 KB
    __shared__ __align__(16) _Float16 s_h0[2][2][64][8];    // h0, 2 kfrags, 4 KB
    __shared__ __align__(16) _Float16 s_h1[2][2][64][8];    // h1, 4 KB
    __shared__ float s_hf[Hh][17];                          // h1(T-1) fp32
    __shared__ float s_fcw[32 * 65];
    __shared__ float s_fc[32][17];

    const int tid = threadIdx.x;
    const int w = tid >> 6;        // wave 0..15
    const int l = tid & 63;        // lane
    const int ar = l & 15;         // A-operand row within tile
    const int akb = l >> 4;        // A/B k-group (k = akb*8 + e)
    const int cq = l >> 4;         // C/D row block
    const int cj = l & 15;         // C/D col = batch
    const int b0 = blockIdx.x * 16;
    const int u = 4 * w + cq;      // unit this lane updates (both layers)

    // ---- persistent A fragments (fp16), permuted row map ----
    // A row ar holds weight row g = (ar&3)*64 + 4w + (ar>>2)
    const int g = (ar & 3) * 64 + 4 * w + (ar >> 2);
    const f16x8 aW0x = cvt8(Wih0 + g * Dd + akb * 8);
    f16x8 aW0h[2], aW1a[2], aW1b[2];
#pragma unroll
    for (int kt = 0; kt < 2; ++kt) {
        aW0h[kt] = cvt8(Whh0 + g * Hh + kt * 32 + akb * 8);
        aW1a[kt] = cvt8(Wih1 + g * Hh + kt * 32 + akb * 8);
        aW1b[kt] = cvt8(Whh1 + g * Hh + kt * 32 + akb * 8);
    }
    // biases: acc[r] is gate r*64 + u
    f32x4 bias0v, bias1v;
#pragma unroll
    for (int r = 0; r < 4; ++r) {
        bias0v[r] = bih0[r * 64 + u] + bhh0[r * 64 + u];
        bias1v[r] = bih1[r * 64 + u] + bhh1[r * 64 + u];
    }

    // h fragment write slot for unit u, batch cj
    const int kt_h = u >> 5;                        // wave-uniform
    const int fl_h = (((u & 31) >> 3) << 4) | cj;
    const int e_h = u & 7;

    // x publish mapping (threads 0..511): (batch bx, dim kx)
    const int kx = tid & 31;
    const int bx = (tid >> 5) & 15;
    const int flx = ((kx >> 3) << 4) | bx;
    const int ex = kx & 7;
    const float* xp = x + ((size_t)(b0 + bx) * Tt) * Dd + kx;

    // zero h frag buffers (h0(-1)=h1(-2)=h1(-1)=0): 1024 ints each
    ((int*)s_h0)[tid] = 0;
    ((int*)s_h1)[tid] = 0;

    float rx0 = 0.f, rx1 = 0.f;
    if (tid < 512) {
        s_x[0][flx][ex] = (_Float16)xp[0];   // x(0) -> parity 0
        rx0 = xp[Dd];                        // x(1)
        rx1 = xp[2 * Dd];                    // x(2)
    }
    float c0 = 0.f, c1 = 0.f;
    __syncthreads();

    for (int t = 0; t < Tt; ++t) {
        const int pr = t & 1;
        // publish x(t+1) into opposite parity; refill prefetch (depth 2)
        if (tid < 512) {
            s_x[pr ^ 1][flx][ex] = (_Float16)rx0;
            rx0 = rx1;
            const int tn = (t + 3 < Tt) ? (t + 3) : (Tt - 1);
            rx1 = xp[(size_t)tn * Dd];
        }
        // fragment reads (all conflict-free contiguous 1KB)
        const f16x8 bxv = *(const f16x8*)&s_x[pr][l][0];
        const f16x8 b0a = *(const f16x8*)&s_h0[pr ^ 1][0][l][0];  // h0(t-1)
        const f16x8 b0b = *(const f16x8*)&s_h0[pr ^ 1][1][l][0];
        const f16x8 b1a = *(const f16x8*)&s_h1[pr][0][l][0];      // h1(t-2)
        const f16x8 b1b = *(const f16x8*)&s_h1[pr][1][l][0];

        // layer0 gates(t)
        f32x4 g0 = bias0v;
        g0 = mfma(aW0x, bxv, g0);
        g0 = mfma(aW0h[0], b0a, g0);
        g0 = mfma(aW0h[1], b0b, g0);
        // layer1 gates(t-1)
        f32x4 g1 = bias1v;
        g1 = mfma(aW1a[0], b0a, g1);
        g1 = mfma(aW1a[1], b0b, g1);
        g1 = mfma(aW1b[0], b1a, g1);
        g1 = mfma(aW1b[1], b1b, g1);

        // in-register cell updates (acc[r] = i,f,g,o of unit u, batch cj)
        const float i0 = sigm(g0[0]), f0 = sigm(g0[1]);
        const float z0 = tanh_(g0[2]), o0 = sigm(g0[3]);
        c0 = f0 * c0 + i0 * z0;
        const float h0v = o0 * tanh_(c0);

        const float i1 = sigm(g1[0]), f1 = sigm(g1[1]);
        const float z1 = tanh_(g1[2]), o1 = sigm(g1[3]);
        float c1n = f1 * c1 + i1 * z1;
        float h1v = o1 * tanh_(c1n);
        if (t == 0) { c1n = 0.f; h1v = 0.f; }  // pipeline warm-up
        c1 = c1n;

        s_h0[pr][kt_h][fl_h][e_h] = (_Float16)h0v;      // h0(t)
        s_h1[pr ^ 1][kt_h][fl_h][e_h] = (_Float16)h1v;  // h1(t-1)
        __syncthreads();
    }

    // ---- epilogue step t=512: layer1 only -> h1(511) ----
    {
        const int pr = 0;  // 512 & 1
        const f16x8 b0a = *(const f16x8*)&s_h0[pr ^ 1][0][l][0];  // h0(511)
        const f16x8 b0b = *(const f16x8*)&s_h0[pr ^ 1][1][l][0];
        const f16x8 b1a = *(const f16x8*)&s_h1[pr][0][l][0];      // h1(510)
        const f16x8 b1b = *(const f16x8*)&s_h1[pr][1][l][0];
        f32x4 g1 = bias1v;
        g1 = mfma(aW1a[0], b0a, g1);
        g1 = mfma(aW1a[1], b0b, g1);
        g1 = mfma(aW1b[0], b1a, g1);
        g1 = mfma(aW1b[1], b1b, g1);
        const float i1 = sigm(g1[0]), f1 = sigm(g1[1]);
        const float z1 = tanh_(g1[2]), o1 = sigm(g1[3]);
        const float c1n = f1 * c1 + i1 * z1;
        s_hf[u][cj] = sigm(g1[3]) * tanh_(c1n) * 0.f + o1 * tanh_(c1n);
    }
    __syncthreads();

    // ---- FC epilogue ----
    for (int i = tid; i < 32 * 64; i += 1024) {
        const int m = i >> 6, uu = i & 63;
        s_fcw[m * 65 + uu] = fc1w[i];
    }
    __syncthreads();
    if (tid < 512) {
        const int m = tid >> 4, jj = tid & 15;
        float acc = fc1b[m];
#pragma unroll
        for (int uu = 0; uu < Hh; ++uu)
            acc = fmaf(s_fcw[m * 65 + uu], s_hf[uu][jj], acc);
        s_fc[m][jj] = fmaxf(acc, 0.f);
    }
    __syncthreads();
    if (tid < 16) {
        float acc = fc2b[0];
#pragma unroll
        for (int m = 0; m < 32; ++m)
            acc = fmaf(fc2w[m], s_fc[m][tid], acc);
        out[b0 + tid] = acc;
    }
}

}  // namespace

extern "C" void kernel_launch(void* const* d_in, const int* in_sizes, int n_in,
                              void* d_out, int out_size, void* d_ws, size_t ws_size,
                              hipStream_t stream) {
    const float* x    = (const float*)d_in[0];
    const float* Wih0 = (const float*)d_in[1];
    const float* Whh0 = (const float*)d_in[2];
    const float* bih0 = (const float*)d_in[3];
    const float* bhh0 = (const float*)d_in[4];
    const float* Wih1 = (const float*)d_in[5];
    const float* Whh1 = (const float*)d_in[6];
    const float* bih1 = (const float*)d_in[7];
    const float* bhh1 = (const float*)d_in[8];
    const float* fc1w = (const float*)d_in[9];
    const float* fc1b = (const float*)d_in[10];
    const float* fc2w = (const float*)d_in[11];
    const float* fc2b = (const float*)d_in[12];
    float* out = (float*)d_out;

    lstm_f16<<<dim3(64), dim3(1024), 0, stream>>>(
        x, Wih0, Whh0, bih0, bhh0, Wih1, Whh1, bih1, bhh1,
        fc1w, fc1b, fc2w, fc2b, out);
}

// Round 4
// 439.313 us; speedup vs baseline: 5.0746x; 1.7774x over previous
//
#include <hip/hip_runtime.h>
#include <math.h>
#include <stdint.h>

// LSTMModel B=1024 T=512 D=32 H=64, 2 layers + fc1(relu) + fc2.
// Round 4: 8 waves x 2 gate-tiles, rcpf activations, lgkm-only barrier.
//   grid = 64 blocks x 512 thr (8 waves); block owns 16 batches, all T.
//   Row permutation: tile i of wave w, A-row ar -> weight row
//   g = (ar&3)*64 + 8w + 2*(ar>>2) + i, so lane (cq,cj) accs hold
//   (i,f,g,o) of units u=8w+2cq+{0,1}, batch cj -> in-register update,
//   packed b32 h-writes. Layer1 lags layer0 by 1 step (skew) -> single
//   lgkm-only barrier per step (x prefetch stays in flight across it).

namespace {

constexpr int Hh = 64, Dd = 32, Tt = 512;

typedef _Float16 f16x8 __attribute__((ext_vector_type(8)));
typedef float f32x4 __attribute__((ext_vector_type(4)));

__device__ __forceinline__ f32x4 mfma(f16x8 a, f16x8 b, f32x4 c) {
    return __builtin_amdgcn_mfma_f32_16x16x32_f16(a, b, c, 0, 0, 0);
}
__device__ __forceinline__ float rcpf(float x) { return __builtin_amdgcn_rcpf(x); }
__device__ __forceinline__ float sigm(float v) { return rcpf(1.0f + __expf(-v)); }
__device__ __forceinline__ float tanh_(float v) {
    return 1.0f - 2.0f * rcpf(__expf(2.0f * v) + 1.0f);
}
__device__ __forceinline__ f16x8 cvt8(const float* p) {
    f16x8 r;
#pragma unroll
    for (int e = 0; e < 8; ++e) r[e] = (_Float16)p[e];
    return r;
}
__device__ __forceinline__ uint32_t pack2(_Float16 a, _Float16 b) {
    union { _Float16 h[2]; uint32_t u; } p;
    p.h[0] = a; p.h[1] = b;
    return p.u;
}
__device__ __forceinline__ void bar_lgkm() {
    // __syncthreads() would drain vmcnt(0) too; only read-only global
    // loads (x prefetch) are outstanding -> lgkm-only is sufficient.
    asm volatile("s_waitcnt lgkmcnt(0)\n\ts_barrier" ::: "memory");
}

__global__ __launch_bounds__(512, 2) void lstm_f16(
    const float* __restrict__ x,     // [B, T, D]
    const float* __restrict__ Wih0,  // [256, 32]
    const float* __restrict__ Whh0,  // [256, 64]
    const float* __restrict__ bih0, const float* __restrict__ bhh0,
    const float* __restrict__ Wih1,  // [256, 64]
    const float* __restrict__ Whh1,  // [256, 64]
    const float* __restrict__ bih1, const float* __restrict__ bhh1,
    const float* __restrict__ fc1w,  // [32, 64]
    const float* __restrict__ fc1b,  // [32]
    const float* __restrict__ fc2w,  // [1, 32]
    const float* __restrict__ fc2b,  // [1]
    float* __restrict__ out)         // [B]
{
    __shared__ __align__(16) _Float16 s_x[2][64][8];      // 2 KB
    __shared__ __align__(16) _Float16 s_h0[2][2][64][8];  // 4 KB
    __shared__ __align__(16) _Float16 s_h1[2][2][64][8];  // 4 KB
    __shared__ float s_hf[Hh][17];
    __shared__ float s_fcw[32 * 65];
    __shared__ float s_fc[32][17];

    const int tid = threadIdx.x;
    const int w = tid >> 6;        // wave 0..7
    const int l = tid & 63;
    const int ar = l & 15;         // A row within tile
    const int akb = l >> 4;        // k-group
    const int cq = l >> 4;         // C/D row block
    const int cj = l & 15;         // C/D col = batch
    const int b0 = blockIdx.x * 16;

    // ---- persistent A fragments, 2 tiles per wave ----
    // tile i row ar -> weight row g = (ar&3)*64 + 8w + 2*(ar>>2) + i
    const int gbase = (ar & 3) * 64 + 8 * w + 2 * (ar >> 2);
    f16x8 A0x[2], A0h[2][2], A1a[2][2], A1b[2][2];
#pragma unroll
    for (int i = 0; i < 2; ++i) {
        const int g = gbase + i;
        A0x[i] = cvt8(Wih0 + g * Dd + akb * 8);
#pragma unroll
        for (int kt = 0; kt < 2; ++kt) {
            A0h[i][kt] = cvt8(Whh0 + g * Hh + kt * 32 + akb * 8);
            A1a[i][kt] = cvt8(Wih1 + g * Hh + kt * 32 + akb * 8);
            A1b[i][kt] = cvt8(Whh1 + g * Hh + kt * 32 + akb * 8);
        }
    }
    // lane owns units ub, ub+1 (both layers)
    const int ub = 8 * w + 2 * cq;
    f32x4 bias0[2], bias1[2];
#pragma unroll
    for (int i = 0; i < 2; ++i)
#pragma unroll
        for (int r = 0; r < 4; ++r) {
            bias0[i][r] = bih0[r * 64 + ub + i] + bhh0[r * 64 + ub + i];
            bias1[i][r] = bih1[r * 64 + ub + i] + bhh1[r * 64 + ub + i];
        }

    // packed h write slot: units (ub, ub+1) batch cj -> dword at elem 2cq
    const int kt_h = w >> 2;
    const int fl_h = (w & 3) * 16 + cj;

    // x publish mapping: 512 threads -> (batch bx, dim kx)
    const int kx = tid & 31;
    const int bx = tid >> 5;  // 0..15
    const int flx = ((kx >> 3) << 4) | bx;
    const int ex = kx & 7;
    const float* xp = x + ((size_t)(b0 + bx) * Tt) * Dd + kx;

    // zero h frag buffers (1024 dwords each, 512 threads)
    ((int*)s_h0)[tid] = 0; ((int*)s_h0)[tid + 512] = 0;
    ((int*)s_h1)[tid] = 0; ((int*)s_h1)[tid + 512] = 0;

    s_x[0][flx][ex] = (_Float16)xp[0];  // x(0)
    float rx0 = xp[Dd];                 // x(1)
    float rx1 = xp[2 * Dd];             // x(2)
    float c0[2] = {0.f, 0.f}, c1[2] = {0.f, 0.f};
    __syncthreads();

    for (int t = 0; t < Tt; ++t) {
        const int pr = t & 1;
        // publish x(t+1) into opposite parity; refill depth-2 prefetch
        s_x[pr ^ 1][flx][ex] = (_Float16)rx0;
        rx0 = rx1;
        const int tn = (t + 3 < Tt) ? (t + 3) : (Tt - 1);
        rx1 = xp[(size_t)tn * Dd];

        // shared B fragments (serve both tiles)
        const f16x8 bxv = *(const f16x8*)&s_x[pr][l][0];
        const f16x8 b0a = *(const f16x8*)&s_h0[pr ^ 1][0][l][0];  // h0(t-1)
        const f16x8 b0b = *(const f16x8*)&s_h0[pr ^ 1][1][l][0];
        const f16x8 b1a = *(const f16x8*)&s_h1[pr][0][l][0];      // h1(t-2)
        const f16x8 b1b = *(const f16x8*)&s_h1[pr][1][l][0];

        f32x4 g0[2], g1[2];
#pragma unroll
        for (int i = 0; i < 2; ++i) {
            f32x4 a = bias0[i];
            a = mfma(A0x[i], bxv, a);
            a = mfma(A0h[i][0], b0a, a);
            a = mfma(A0h[i][1], b0b, a);
            g0[i] = a;
            f32x4 b = bias1[i];
            b = mfma(A1a[i][0], b0a, b);
            b = mfma(A1a[i][1], b0b, b);
            b = mfma(A1b[i][0], b1a, b);
            b = mfma(A1b[i][1], b1b, b);
            g1[i] = b;
        }

        _Float16 h0p[2], h1p[2];
#pragma unroll
        for (int i = 0; i < 2; ++i) {
            const float i0 = sigm(g0[i][0]), f0 = sigm(g0[i][1]);
            const float z0 = tanh_(g0[i][2]), o0 = sigm(g0[i][3]);
            c0[i] = f0 * c0[i] + i0 * z0;
            h0p[i] = (_Float16)(o0 * tanh_(c0[i]));
            const float i1 = sigm(g1[i][0]), f1 = sigm(g1[i][1]);
            const float z1 = tanh_(g1[i][2]), o1 = sigm(g1[i][3]);
            float c1n = f1 * c1[i] + i1 * z1;
            float h1v = o1 * tanh_(c1n);
            if (t == 0) { c1n = 0.f; h1v = 0.f; }  // pipeline warm-up
            c1[i] = c1n;
            h1p[i] = (_Float16)h1v;
        }
        *(uint32_t*)&s_h0[pr][kt_h][fl_h][2 * cq]     = pack2(h0p[0], h0p[1]);
        *(uint32_t*)&s_h1[pr ^ 1][kt_h][fl_h][2 * cq] = pack2(h1p[0], h1p[1]);
        bar_lgkm();
    }

    // ---- epilogue step: layer1 -> h1(511) from h0(511), h1(510) ----
    {
        const f16x8 b0a = *(const f16x8*)&s_h0[1][0][l][0];
        const f16x8 b0b = *(const f16x8*)&s_h0[1][1][l][0];
        const f16x8 b1a = *(const f16x8*)&s_h1[0][0][l][0];
        const f16x8 b1b = *(const f16x8*)&s_h1[0][1][l][0];
#pragma unroll
        for (int i = 0; i < 2; ++i) {
            f32x4 b = bias1[i];
            b = mfma(A1a[i][0], b0a, b);
            b = mfma(A1a[i][1], b0b, b);
            b = mfma(A1b[i][0], b1a, b);
            b = mfma(A1b[i][1], b1b, b);
            const float i1 = sigm(b[0]), f1 = sigm(b[1]);
            const float z1 = tanh_(b[2]), o1 = sigm(b[3]);
            const float c1n = f1 * c1[i] + i1 * z1;
            s_hf[ub + i][cj] = o1 * tanh_(c1n);
        }
    }
    __syncthreads();

    // ---- FC epilogue ----
    for (int i2 = tid; i2 < 32 * 64; i2 += 512) {
        const int m = i2 >> 6, uu = i2 & 63;
        s_fcw[m * 65 + uu] = fc1w[i2];
    }
    __syncthreads();
    {
        const int m = tid >> 4, jj = tid & 15;  // all 512 threads
        float acc = fc1b[m];
#pragma unroll
        for (int uu = 0; uu < Hh; ++uu)
            acc = fmaf(s_fcw[m * 65 + uu], s_hf[uu][jj], acc);
        s_fc[m][jj] = fmaxf(acc, 0.f);
    }
    __syncthreads();
    if (tid < 16) {
        float acc = fc2b[0];
#pragma unroll
        for (int m = 0; m < 32; ++m)
            acc = fmaf(fc2w[m], s_fc[m][tid], acc);
        out[b0 + tid] = acc;
    }
}

}  // namespace

extern "C" void kernel_launch(void* const* d_in, const int* in_sizes, int n_in,
                              void* d_out, int out_size, void* d_ws, size_t ws_size,
                              hipStream_t stream) {
    const float* x    = (const float*)d_in[0];
    const float* Wih0 = (const float*)d_in[1];
    const float* Whh0 = (const float*)d_in[2];
    const float* bih0 = (const float*)d_in[3];
    const float* bhh0 = (const float*)d_in[4];
    const float* Wih1 = (const float*)d_in[5];
    const float* Whh1 = (const float*)d_in[6];
    const float* bih1 = (const float*)d_in[7];
    const float* bhh1 = (const float*)d_in[8];
    const float* fc1w = (const float*)d_in[9];
    const float* fc1b = (const float*)d_in[10];
    const float* fc2w = (const float*)d_in[11];
    const float* fc2b = (const float*)d_in[12];
    float* out = (float*)d_out;

    lstm_f16<<<dim3(64), dim3(512), 0, stream>>>(
        x, Wih0, Whh0, bih0, bhh0, Wih1, Whh1, bih1, bhh1,
        fc1w, fc1b, fc2w, fc2b, out);
}

// Round 5
// 327.008 us; speedup vs baseline: 6.8174x; 1.3434x over previous
//
#include <hip/hip_runtime.h>
#include <math.h>
#include <stdint.h>

// LSTMModel B=1024 T=512 D=32 H=64, 2 layers + fc1(relu) + fc2.
// Round 5: 128 blocks x 8 batches, dup-2 B-frag columns, layer-split lanes.
//   Every B-fragment holds batch cols [b0..b7, b0..b7]; lanes cj<8 take
//   layer-0 gates, cj>=8 take layer-1 -> per-lane cell updates 4 -> 2,
//   branch-free (cndmask selects). log2e folded into weights/biases so
//   activations are bare v_exp_f32 + v_rcp_f32. Same skew pipeline +
//   single lgkm-only barrier per step as R4.

namespace {

constexpr int Hh = 64, Dd = 32, Tt = 512;
constexpr float LOG2E = 1.4426950408889634f;

typedef _Float16 f16x8 __attribute__((ext_vector_type(8)));
typedef float f32x4 __attribute__((ext_vector_type(4)));

__device__ __forceinline__ f32x4 mfma(f16x8 a, f16x8 b, f32x4 c) {
    return __builtin_amdgcn_mfma_f32_16x16x32_f16(a, b, c, 0, 0, 0);
}
__device__ __forceinline__ float rcpf(float x) { return __builtin_amdgcn_rcpf(x); }
__device__ __forceinline__ float exp2f_(float x) { return __builtin_amdgcn_exp2f(x); }
// preact pre-scaled by LOG2E:
__device__ __forceinline__ float sigm_s(float p) { return rcpf(1.0f + exp2f_(-p)); }
// preact pre-scaled by 2*LOG2E:
__device__ __forceinline__ float tanh_s(float p) {
    return 1.0f - 2.0f * rcpf(exp2f_(p) + 1.0f);
}
// natural units:
__device__ __forceinline__ float tanh_n(float c) {
    return 1.0f - 2.0f * rcpf(exp2f_(c * (2.0f * LOG2E)) + 1.0f);
}
__device__ __forceinline__ f16x8 cvt8s(const float* p, float sc) {
    f16x8 r;
#pragma unroll
    for (int e = 0; e < 8; ++e) r[e] = (_Float16)(p[e] * sc);
    return r;
}
__device__ __forceinline__ uint32_t pack2(_Float16 a, _Float16 b) {
    union { _Float16 h[2]; uint32_t u; } p;
    p.h[0] = a; p.h[1] = b;
    return p.u;
}
__device__ __forceinline__ void bar_lgkm() {
    asm volatile("s_waitcnt lgkmcnt(0)\n\ts_barrier" ::: "memory");
}

__global__ __launch_bounds__(512, 2) void lstm_f16(
    const float* __restrict__ x,     // [B, T, D]
    const float* __restrict__ Wih0,  // [256, 32]
    const float* __restrict__ Whh0,  // [256, 64]
    const float* __restrict__ bih0, const float* __restrict__ bhh0,
    const float* __restrict__ Wih1,  // [256, 64]
    const float* __restrict__ Whh1,  // [256, 64]
    const float* __restrict__ bih1, const float* __restrict__ bhh1,
    const float* __restrict__ fc1w,  // [32, 64]
    const float* __restrict__ fc1b,  // [32]
    const float* __restrict__ fc2w,  // [1, 32]
    const float* __restrict__ fc2b,  // [1]
    float* __restrict__ out)         // [B]
{
    __shared__ __align__(16) _Float16 s_x[2][64][8];      // 2 KB
    __shared__ __align__(16) _Float16 s_h0[2][2][64][8];  // 4 KB
    __shared__ __align__(16) _Float16 s_h1[2][2][64][8];  // 4 KB
    __shared__ float s_hf[Hh][9];
    __shared__ float s_fcw[32 * 65];
    __shared__ float s_fc[32][9];

    const int tid = threadIdx.x;
    const int w = tid >> 6;        // wave 0..7
    const int l = tid & 63;
    const int ar = l & 15;         // A row within tile
    const int akb = l >> 4;        // k-group
    const int cq = l >> 4;         // C/D row block
    const int cj = l & 15;         // C/D col
    const int b0 = blockIdx.x * 8; // 8 batches per block
    const bool isL1 = (cj >= 8);
    const int cb = cj & 7;         // real batch col

    // ---- persistent A fragments, log2e-folded, 2 tiles per wave ----
    // tile i row ar -> weight row g = (ar&3)*64 + 8w + 2*(ar>>2) + i
    const int r4 = ar & 3;                    // gate (i,f,g,o)
    const float sc = (r4 == 2) ? 2.0f * LOG2E : LOG2E;
    const int gbase = r4 * 64 + 8 * w + 2 * (ar >> 2);
    f16x8 A0x[2], A0h[2][2], A1a[2][2], A1b[2][2];
#pragma unroll
    for (int i = 0; i < 2; ++i) {
        const int g = gbase + i;
        A0x[i] = cvt8s(Wih0 + g * Dd + akb * 8, sc);
#pragma unroll
        for (int kt = 0; kt < 2; ++kt) {
            A0h[i][kt] = cvt8s(Whh0 + g * Hh + kt * 32 + akb * 8, sc);
            A1a[i][kt] = cvt8s(Wih1 + g * Hh + kt * 32 + akb * 8, sc);
            A1b[i][kt] = cvt8s(Whh1 + g * Hh + kt * 32 + akb * 8, sc);
        }
    }
    // lane owns units ub, ub+1 of its layer (cj<8 -> L0, cj>=8 -> L1)
    const int ub = 8 * w + 2 * cq;
    f32x4 bias0[2], bias1[2];
#pragma unroll
    for (int i = 0; i < 2; ++i)
#pragma unroll
        for (int r = 0; r < 4; ++r) {
            const float s2 = (r == 2) ? 2.0f * LOG2E : LOG2E;
            bias0[i][r] = s2 * (bih0[r * 64 + ub + i] + bhh0[r * 64 + ub + i]);
            bias1[i][r] = s2 * (bih1[r * 64 + ub + i] + bhh1[r * 64 + ub + i]);
        }

    // h write slot: (units ub,ub+1, col cb) ; dup col at +64 elems (128 B)
    const int kt_h = w >> 2;
    const int fl_h = (w & 3) * 16 + cb;
    // L0 writes s_h0[pr], L1 writes s_h1[pr^1]; per-lane base + parity delta
    _Float16* const wbase = isL1 ? &s_h1[1][kt_h][fl_h][2 * cq]
                                 : &s_h0[0][kt_h][fl_h][2 * cq];
    const int wdelta = isL1 ? -1024 : 1024;  // elems per parity flip

    // x publish mapping: threads 0..255 -> (batch bx, dim kx)
    const int kx = tid & 31;
    const int bx = (tid >> 5) & 7;
    const int flx = ((kx >> 3) << 4) | bx;
    const int ex = kx & 7;
    const float* xp = x + ((size_t)(b0 + bx) * Tt) * Dd + kx;

    // zero h frag buffers (1024 dwords each, 512 threads)
    ((int*)s_h0)[tid] = 0; ((int*)s_h0)[tid + 512] = 0;
    ((int*)s_h1)[tid] = 0; ((int*)s_h1)[tid + 512] = 0;

    float rx0 = 0.f, rx1 = 0.f;
    if (tid < 256) {
        const _Float16 v0 = (_Float16)xp[0];
        s_x[0][flx][ex] = v0;            // x(0), both dup halves
        s_x[0][flx + 8][ex] = v0;
        rx0 = xp[Dd];
        rx1 = xp[2 * Dd];
    }
    float cst[2] = {0.f, 0.f};
    __syncthreads();

    for (int t = 0; t < Tt; ++t) {
        const int pr = t & 1;
        if (tid < 256) {
            const _Float16 v = (_Float16)rx0;
            s_x[pr ^ 1][flx][ex] = v;
            s_x[pr ^ 1][flx + 8][ex] = v;
            rx0 = rx1;
            const int tn = (t + 3 < Tt) ? (t + 3) : (Tt - 1);
            rx1 = xp[(size_t)tn * Dd];
        }
        const f16x8 bxv = *(const f16x8*)&s_x[pr][l][0];
        const f16x8 b0a = *(const f16x8*)&s_h0[pr ^ 1][0][l][0];  // h0(t-1)
        const f16x8 b0b = *(const f16x8*)&s_h0[pr ^ 1][1][l][0];
        const f16x8 b1a = *(const f16x8*)&s_h1[pr][0][l][0];      // h1(t-2)
        const f16x8 b1b = *(const f16x8*)&s_h1[pr][1][l][0];

        f32x4 gg[2];
#pragma unroll
        for (int i = 0; i < 2; ++i) {
            f32x4 a = bias0[i];
            a = mfma(A0x[i], bxv, a);
            a = mfma(A0h[i][0], b0a, a);
            a = mfma(A0h[i][1], b0b, a);
            f32x4 b = bias1[i];
            b = mfma(A1a[i][0], b0a, b);
            b = mfma(A1a[i][1], b0b, b);
            b = mfma(A1b[i][0], b1a, b);
            b = mfma(A1b[i][1], b1b, b);
#pragma unroll
            for (int r = 0; r < 4; ++r) gg[i][r] = isL1 ? b[r] : a[r];
        }

        _Float16 hp[2];
#pragma unroll
        for (int i = 0; i < 2; ++i) {
            const float gi = sigm_s(gg[i][0]);
            const float gf = sigm_s(gg[i][1]);
            const float zz = tanh_s(gg[i][2]);
            const float go = sigm_s(gg[i][3]);
            float cn = gf * cst[i] + gi * zz;
            float hv = go * tanh_n(cn);
            if (t == 0) {            // wave-uniform; zero L1 warm-up step
                cn = isL1 ? 0.f : cn;
                hv = isL1 ? 0.f : hv;
            }
            cst[i] = cn;
            hp[i] = (_Float16)hv;
        }
        const uint32_t packed = pack2(hp[0], hp[1]);
        _Float16* wp = wbase + (pr ? wdelta : 0);
        *(uint32_t*)wp = packed;          // real col
        *(uint32_t*)(wp + 64) = packed;   // dup col (+128 B)
        bar_lgkm();
    }

    // ---- epilogue: layer1 step for h1(511) from h0(511), h1(510) ----
    {
        const f16x8 b0a = *(const f16x8*)&s_h0[1][0][l][0];
        const f16x8 b0b = *(const f16x8*)&s_h0[1][1][l][0];
        const f16x8 b1a = *(const f16x8*)&s_h1[0][0][l][0];
        const f16x8 b1b = *(const f16x8*)&s_h1[0][1][l][0];
#pragma unroll
        for (int i = 0; i < 2; ++i) {
            f32x4 b = bias1[i];
            b = mfma(A1a[i][0], b0a, b);
            b = mfma(A1a[i][1], b0b, b);
            b = mfma(A1b[i][0], b1a, b);
            b = mfma(A1b[i][1], b1b, b);
            if (isL1) {  // these lanes hold c1(510)
                const float gi = sigm_s(b[0]);
                const float gf = sigm_s(b[1]);
                const float zz = tanh_s(b[2]);
                const float go = sigm_s(b[3]);
                const float cn = gf * cst[i] + gi * zz;
                s_hf[ub + i][cb] = go * tanh_n(cn);
            }
        }
    }
    __syncthreads();

    // ---- FC epilogue (8 batches) ----
    for (int i2 = tid; i2 < 32 * 64; i2 += 512) {
        const int m = i2 >> 6, uu = i2 & 63;
        s_fcw[m * 65 + uu] = fc1w[i2];
    }
    __syncthreads();
    if (tid < 256) {
        const int m = tid >> 3, jj = tid & 7;
        float acc = fc1b[m];
#pragma unroll
        for (int uu = 0; uu < Hh; ++uu)
            acc = fmaf(s_fcw[m * 65 + uu], s_hf[uu][jj], acc);
        s_fc[m][jj] = fmaxf(acc, 0.f);
    }
    __syncthreads();
    if (tid < 8) {
        float acc = fc2b[0];
#pragma unroll
        for (int m = 0; m < 32; ++m)
            acc = fmaf(fc2w[m], s_fc[m][tid], acc);
        out[b0 + tid] = acc;
    }
}

}  // namespace

extern "C" void kernel_launch(void* const* d_in, const int* in_sizes, int n_in,
                              void* d_out, int out_size, void* d_ws, size_t ws_size,
                              hipStream_t stream) {
    const float* x    = (const float*)d_in[0];
    const float* Wih0 = (const float*)d_in[1];
    const float* Whh0 = (const float*)d_in[2];
    const float* bih0 = (const float*)d_in[3];
    const float* bhh0 = (const float*)d_in[4];
    const float* Wih1 = (const float*)d_in[5];
    const float* Whh1 = (const float*)d_in[6];
    const float* bih1 = (const float*)d_in[7];
    const float* bhh1 = (const float*)d_in[8];
    const float* fc1w = (const float*)d_in[9];
    const float* fc1b = (const float*)d_in[10];
    const float* fc2w = (const float*)d_in[11];
    const float* fc2b = (const float*)d_in[12];
    float* out = (float*)d_out;

    lstm_f16<<<dim3(128), dim3(512), 0, stream>>>(
        x, Wih0, Whh0, bih0, bhh0, Wih1, Whh1, bih1, bhh1,
        fc1w, fc1b, fc2w, fc2b, out);
}